// Round 4
// baseline (715.806 us; speedup 1.0000x reference)
//
#include <hip/hip_runtime.h>

// y[rows[k]] += vals[k] * x[cols[k]]  — M=N=262144, NNZ=8388608, out 512x512 f32.
// Single persistent kernel: scatter (counting-sort into 32 row-bins) -> grid sync
// -> per-(bin,slice) LDS accumulation -> grid sync -> slice reduction.
// Manual grid barrier: grid==1024 blocks x 256thr x 32KB LDS, launch_bounds(256,4)
// guarantees >=4 blocks/CU co-resident (LDS cap 5/CU, wave cap 8/CU).

#define BINS         32
#define ROW_SHIFT    13            // 8192 rows per bin
#define ROWS_PER_BIN 8192
#define ENT          4096          // entries per scatter segment (16/thread)
#define CUR_STRIDE   32            // global cursor padding: 1 counter per 128B line

typedef int   i32x4 __attribute__((ext_vector_type(4)));
typedef float f32x4 __attribute__((ext_vector_type(4)));

// ---------------- fallback path (known-correct) ----------------

__global__ __launch_bounds__(256) void zero_out_kernel(float* __restrict__ y, int n) {
    int i = blockIdx.x * blockDim.x + threadIdx.x;
    if (i < n) y[i] = 0.0f;
}

__global__ __launch_bounds__(256) void spmv_coo_scatter(
    const float* __restrict__ vals, const int* __restrict__ rows,
    const int* __restrict__ cols, const float* __restrict__ x,
    float* __restrict__ y, int nnz)
{
    int i = (blockIdx.x * blockDim.x + threadIdx.x) * 4;
    if (i + 3 < nnz) {
        float4 v = *reinterpret_cast<const float4*>(vals + i);
        int4   r = *reinterpret_cast<const int4*>(rows + i);
        int4   c = *reinterpret_cast<const int4*>(cols + i);
        atomicAdd(&y[r.x], v.x * x[c.x]);
        atomicAdd(&y[r.y], v.y * x[c.y]);
        atomicAdd(&y[r.z], v.z * x[c.z]);
        atomicAdd(&y[r.w], v.w * x[c.w]);
    } else {
        for (; i < nnz; ++i) atomicAdd(&y[rows[i]], vals[i] * x[cols[i]]);
    }
}

// ---------------- persistent binned path ----------------

__global__ __launch_bounds__(256) void init_kernel(
    unsigned* __restrict__ gcur, int ncur, unsigned* __restrict__ bar)
{
    int i = blockIdx.x * 256 + threadIdx.x;
    if (i < ncur) gcur[i] = 0u;
    if (blockIdx.x == 0 && threadIdx.x < 2) bar[threadIdx.x] = 0u;  // [0]=arrive [1]=gen
}

// Device-scope grid barrier. Release fence before arrive makes this block's global
// stores visible at the coherent point; acquire on gen + fence after makes them
// visible to this block. Cross-XCD safe (agent scope).
__device__ __forceinline__ void grid_sync(unsigned* bar, unsigned nb) {
    __syncthreads();
    if (threadIdx.x == 0) {
        __threadfence();
        unsigned g = __hip_atomic_load(&bar[1], __ATOMIC_RELAXED, __HIP_MEMORY_SCOPE_AGENT);
        unsigned a = __hip_atomic_fetch_add(&bar[0], 1u, __ATOMIC_ACQ_REL, __HIP_MEMORY_SCOPE_AGENT);
        if (a + 1u == nb) {
            __hip_atomic_store(&bar[0], 0u, __ATOMIC_RELAXED, __HIP_MEMORY_SCOPE_AGENT);
            __hip_atomic_fetch_add(&bar[1], 1u, __ATOMIC_RELEASE, __HIP_MEMORY_SCOPE_AGENT);
        } else {
            while (__hip_atomic_load(&bar[1], __ATOMIC_ACQUIRE, __HIP_MEMORY_SCOPE_AGENT) == g)
                __builtin_amdgcn_s_sleep(8);
        }
        __threadfence();
    }
    __syncthreads();
}

template <int SL>
__global__ __launch_bounds__(256, 4) void mega_kernel(
    const int*   __restrict__ rows, const int* __restrict__ cols,
    const float* __restrict__ vals, const float* __restrict__ x, int nnz,
    unsigned* __restrict__ gcur, unsigned cap,
    unsigned short* __restrict__ okeys, float* __restrict__ ocontrib,
    float* __restrict__ partials, float* __restrict__ y,
    unsigned* __restrict__ bar, int out_size)
{
    __shared__ union {
        struct {
            unsigned short skey[ENT];     //  8192 B
            float          sval[ENT];     // 16384 B
            unsigned char  sbin[ENT];     //  4096 B
            unsigned cnt[BINS];
            int      dstb[BINS];
            unsigned cur2[BINS];
            unsigned total;
        } s;
        float acc[ROWS_PER_BIN];          // 32768 B
    } sm;

    const int t    = threadIdx.x;
    const int blk  = blockIdx.x;
    const int grid = BINS * SL;
    const int nseg = (nnz + ENT - 1) / ENT;

    // ================= phase 1: scatter (counting sort per segment) =============
    for (int s = blk; s < nseg; s += grid) {
        __syncthreads();                       // protect smem reuse across segments
        if (t < BINS) sm.s.cnt[t] = 0u;
        __syncthreads();

        const int seg = s * ENT;
        int   rr[16];
        int   cc[16];
        float ff[16];

        if (seg + ENT <= nnz) {
            #pragma unroll
            for (int ch = 0; ch < 4; ++ch) {
                int base = seg + ch * 1024 + t * 4;
                i32x4 r4 = *reinterpret_cast<const i32x4*>(rows + base);
                i32x4 c4 = *reinterpret_cast<const i32x4*>(cols + base);
                f32x4 v4 = *reinterpret_cast<const f32x4*>(vals + base);
                rr[ch*4+0] = r4.x; cc[ch*4+0] = c4.x; ff[ch*4+0] = v4.x;
                rr[ch*4+1] = r4.y; cc[ch*4+1] = c4.y; ff[ch*4+1] = v4.y;
                rr[ch*4+2] = r4.z; cc[ch*4+2] = c4.z; ff[ch*4+2] = v4.z;
                rr[ch*4+3] = r4.w; cc[ch*4+3] = c4.w; ff[ch*4+3] = v4.w;
            }
            #pragma unroll
            for (int j = 0; j < 16; ++j) ff[j] *= x[cc[j]];
        } else {
            #pragma unroll
            for (int ch = 0; ch < 4; ++ch) {
                #pragma unroll
                for (int j = 0; j < 4; ++j) {
                    int idx = seg + ch * 1024 + t * 4 + j;
                    if (idx < nnz) { rr[ch*4+j] = rows[idx]; cc[ch*4+j] = cols[idx]; ff[ch*4+j] = vals[idx]; }
                    else           { rr[ch*4+j] = -1; cc[ch*4+j] = 0; ff[ch*4+j] = 0.0f; }
                }
            }
            #pragma unroll
            for (int j = 0; j < 16; ++j) if (rr[j] >= 0) ff[j] *= x[cc[j]];
        }

        #pragma unroll
        for (int j = 0; j < 16; ++j)
            if (rr[j] >= 0) atomicAdd(&sm.s.cnt[rr[j] >> ROW_SHIFT], 1u);
        __syncthreads();

        // Reserve global space per bin + shfl exclusive scan (wave 0).
        if (t < BINS) {
            unsigned c = sm.s.cnt[t];
            unsigned resv = atomicAdd(&gcur[t * CUR_STRIDE], c);
            unsigned v = c;
            #pragma unroll
            for (int d = 1; d < BINS; d <<= 1) {
                unsigned o = __shfl_up(v, d, 64);
                if (t >= d) v += o;
            }
            unsigned ls = v - c;
            sm.s.cur2[t] = ls;
            sm.s.dstb[t] = (int)resv - (int)ls;
            if (t == BINS - 1) sm.s.total = v;
        }
        __syncthreads();

        #pragma unroll
        for (int j = 0; j < 16; ++j) {
            if (rr[j] >= 0) {
                int b = rr[j] >> ROW_SHIFT;
                unsigned p = atomicAdd(&sm.s.cur2[b], 1u);
                sm.s.skey[p] = (unsigned short)(rr[j] & (ROWS_PER_BIN - 1));
                sm.s.sval[p] = ff[j];
                sm.s.sbin[p] = (unsigned char)b;
            }
        }
        __syncthreads();

        const unsigned total = sm.s.total;
        for (unsigned i = t; i < total; i += 256) {
            int b = sm.s.sbin[i];
            unsigned off = (unsigned)(sm.s.dstb[b] + (int)i);
            if (off < cap) {
                size_t dst = (size_t)b * cap + off;
                okeys[dst]    = sm.s.skey[i];
                ocontrib[dst] = sm.s.sval[i];
            }
        }
    }

    grid_sync(bar, (unsigned)grid);

    // ================= phase 2: accum (bin,slice) -> partials ===================
    {
        const int bin = blk / SL;
        const int sl  = blk - bin * SL;

        float4 z = make_float4(0.f, 0.f, 0.f, 0.f);
        #pragma unroll
        for (int i = 0; i < ROWS_PER_BIN / (256 * 4); ++i)
            *reinterpret_cast<float4*>(&sm.acc[(i * 256 + t) * 4]) = z;
        __syncthreads();

        unsigned count = gcur[bin * CUR_STRIDE];
        if (count > cap) count = cap;
        unsigned chunk = ((count + (unsigned)SL - 1u) / (unsigned)SL + 3u) & ~3u;
        unsigned lo = (unsigned)sl * chunk;
        unsigned hi = lo + chunk; if (hi > count) hi = count;

        const unsigned short* k = okeys    + (size_t)bin * cap;
        const float*          c = ocontrib + (size_t)bin * cap;

        unsigned i = lo + (unsigned)t * 4u;

        // 8x batch: 16 independent vector loads in flight before any LDS atomic.
        for (; i + 7171u < hi; i += 8192u) {
            ushort4 K[8];
            float4  C[8];
            #pragma unroll
            for (int j = 0; j < 8; ++j) K[j] = *reinterpret_cast<const ushort4*>(k + i + (unsigned)j * 1024u);
            #pragma unroll
            for (int j = 0; j < 8; ++j) C[j] = *reinterpret_cast<const float4*>(c + i + (unsigned)j * 1024u);
            #pragma unroll
            for (int j = 0; j < 8; ++j) {
                atomicAdd(&sm.acc[K[j].x], C[j].x);
                atomicAdd(&sm.acc[K[j].y], C[j].y);
                atomicAdd(&sm.acc[K[j].z], C[j].z);
                atomicAdd(&sm.acc[K[j].w], C[j].w);
            }
        }
        for (; i + 3u < hi; i += 1024u) {
            ushort4 k4 = *reinterpret_cast<const ushort4*>(k + i);
            float4  c4 = *reinterpret_cast<const float4*>(c + i);
            atomicAdd(&sm.acc[k4.x], c4.x);
            atomicAdd(&sm.acc[k4.y], c4.y);
            atomicAdd(&sm.acc[k4.z], c4.z);
            atomicAdd(&sm.acc[k4.w], c4.w);
        }
        for (; i < hi; ++i) atomicAdd(&sm.acc[k[i]], c[i]);
        __syncthreads();

        float* p = partials + (size_t)blk * ROWS_PER_BIN;
        #pragma unroll
        for (int i2 = 0; i2 < ROWS_PER_BIN / (256 * 4); ++i2) {
            int l = (i2 * 256 + t) * 4;
            *reinterpret_cast<float4*>(p + l) = *reinterpret_cast<const float4*>(&sm.acc[l]);
        }
    }

    grid_sync(bar, (unsigned)grid);

    // ================= phase 3: reduce partials -> y ============================
    {
        const int rpb = out_size / grid;          // 256 (SL=32) or 512 (SL=16)
        const int r0  = blk * rpb;
        for (int r = r0 + t; r < r0 + rpb; r += 256) {
            int bin   = r >> ROW_SHIFT;
            int local = r & (ROWS_PER_BIN - 1);
            const float* p = partials + ((size_t)bin * SL) * ROWS_PER_BIN + local;
            float ssum = 0.0f;
            #pragma unroll
            for (int j = 0; j < SL; ++j) ssum += p[(size_t)j * ROWS_PER_BIN];
            y[r] = ssum;
        }
    }
}

extern "C" void kernel_launch(void* const* d_in, const int* in_sizes, int n_in,
                              void* d_out, int out_size, void* d_ws, size_t ws_size,
                              hipStream_t stream) {
    const float* x    = (const float*)d_in[0];
    const float* vals = (const float*)d_in[1];
    const int*   rows = (const int*)d_in[2];
    const int*   cols = (const int*)d_in[3];
    float* y = (float*)d_out;

    const int nnz  = in_sizes[1];
    const int bins = (out_size + ROWS_PER_BIN - 1) / ROWS_PER_BIN;

    unsigned cap = (unsigned)(nnz / (bins > 0 ? bins : 1)) + 16384u;
    cap = (cap + 3u) & ~3u;

    auto align256 = [](size_t v) { return (v + 255) & ~(size_t)255; };

    int slices = 32;
    size_t off_contrib = 0, off_keys = 0, off_partials = 0, off_gcur = 0, off_bar = 0, need = 0;
    for (int attempt = 0; attempt < 2; ++attempt) {
        off_contrib  = 0;
        off_keys     = align256(off_contrib + (size_t)BINS * cap * 4);
        off_partials = align256(off_keys + (size_t)BINS * cap * 2);
        off_gcur     = align256(off_partials + (size_t)BINS * slices * ROWS_PER_BIN * 4);
        off_bar      = align256(off_gcur + (size_t)BINS * CUR_STRIDE * 4);
        need         = align256(off_bar + 256);
        if (need <= ws_size) break;
        slices = 16;
    }

    const bool ok = (bins == BINS) && (need <= ws_size) && (nnz > 0) &&
                    (out_size == BINS * ROWS_PER_BIN);

    if (!ok) {
        zero_out_kernel<<<(out_size + 255) / 256, 256, 0, stream>>>(y, out_size);
        spmv_coo_scatter<<<(nnz + 1023) / 1024, 256, 0, stream>>>(vals, rows, cols, x, y, nnz);
        return;
    }

    char* w = (char*)d_ws;
    float*          ocontrib = (float*)(w + off_contrib);
    unsigned short* okeys    = (unsigned short*)(w + off_keys);
    float*          partials = (float*)(w + off_partials);
    unsigned*       gcur     = (unsigned*)(w + off_gcur);
    unsigned*       bar      = (unsigned*)(w + off_bar);

    const int ncur = BINS * CUR_STRIDE;
    init_kernel<<<(ncur + 255) / 256, 256, 0, stream>>>(gcur, ncur, bar);

    if (slices == 32) {
        mega_kernel<32><<<BINS * 32, 256, 0, stream>>>(
            rows, cols, vals, x, nnz, gcur, cap, okeys, ocontrib, partials, y, bar, out_size);
    } else {
        mega_kernel<16><<<BINS * 16, 256, 0, stream>>>(
            rows, cols, vals, x, nnz, gcur, cap, okeys, ocontrib, partials, y, bar, out_size);
    }
}

// Round 5
// 225.302 us; speedup vs baseline: 3.1771x; 3.1771x over previous
//
#include <hip/hip_runtime.h>

// y[rows[k]] += vals[k] * x[cols[k]]  — M=N=262144, NNZ=8388608, out 512x512 f32.
// Split pipeline (grid barriers are poison on gfx950 — R4 showed agent-scope sync
// forces cross-XCD L2 flush traffic): init cursors -> counting-sort scatter into
// 32 row-bins (no sbin array: per-bin copy-out; 24.5KB LDS -> 6 blocks/CU) ->
// per-(bin,slice) LDS accumulation at 100% occupancy -> slice reduction.

#define BINS         32
#define ROW_SHIFT    13            // 8192 rows per bin
#define ROWS_PER_BIN 8192
#define ENT          4096          // entries per scatter block (16/thread)
#define CUR_STRIDE   32            // global cursor padding: 1 counter per 128B line

typedef int   i32x4 __attribute__((ext_vector_type(4)));
typedef float f32x4 __attribute__((ext_vector_type(4)));

// ---------------- fallback path (known-correct) ----------------

__global__ __launch_bounds__(256) void zero_out_kernel(float* __restrict__ y, int n) {
    int i = blockIdx.x * blockDim.x + threadIdx.x;
    if (i < n) y[i] = 0.0f;
}

__global__ __launch_bounds__(256) void spmv_coo_scatter(
    const float* __restrict__ vals, const int* __restrict__ rows,
    const int* __restrict__ cols, const float* __restrict__ x,
    float* __restrict__ y, int nnz)
{
    int i = (blockIdx.x * blockDim.x + threadIdx.x) * 4;
    if (i + 3 < nnz) {
        float4 v = *reinterpret_cast<const float4*>(vals + i);
        int4   r = *reinterpret_cast<const int4*>(rows + i);
        int4   c = *reinterpret_cast<const int4*>(cols + i);
        atomicAdd(&y[r.x], v.x * x[c.x]);
        atomicAdd(&y[r.y], v.y * x[c.y]);
        atomicAdd(&y[r.z], v.z * x[c.z]);
        atomicAdd(&y[r.w], v.w * x[c.w]);
    } else {
        for (; i < nnz; ++i) atomicAdd(&y[rows[i]], vals[i] * x[cols[i]]);
    }
}

// ---------------- binned path ----------------

__global__ __launch_bounds__(256) void init_cursors(unsigned* __restrict__ gcur, int n) {
    int i = blockIdx.x * 256 + threadIdx.x;
    if (i < n) gcur[i] = 0u;
}

// Block-local counting sort + per-bin coalesced copy-out into bin regions.
// LDS = 24.5 KB -> 6 blocks/CU -> 24 waves (75% occupancy), up from 40%.
__global__ __launch_bounds__(256) void scatter2_kernel(
    const int*   __restrict__ rows, const int* __restrict__ cols,
    const float* __restrict__ vals, const float* __restrict__ x, int nnz,
    unsigned* __restrict__ gcur, unsigned cap,
    unsigned short* __restrict__ okeys, float* __restrict__ ocontrib)
{
    __shared__ unsigned short skey[ENT];     //  8192 B
    __shared__ float          sval[ENT];     // 16384 B
    __shared__ unsigned cnt[BINS];
    __shared__ unsigned lstart[BINS];
    __shared__ unsigned resv[BINS];
    __shared__ unsigned cur2[BINS];

    const int t = threadIdx.x;
    if (t < BINS) cnt[t] = 0u;
    __syncthreads();

    const int seg = blockIdx.x * ENT;

    int   rr[16];
    int   cc[16];
    float ff[16];

    // Pass A: load triplets; keep all 16 col indices so the 16 x-gathers issue
    // as one independent batch (MLP), then multiply.
    if (seg + ENT <= nnz) {
        #pragma unroll
        for (int ch = 0; ch < 4; ++ch) {
            int base = seg + ch * 1024 + t * 4;
            i32x4 r4 = *reinterpret_cast<const i32x4*>(rows + base);
            i32x4 c4 = *reinterpret_cast<const i32x4*>(cols + base);
            f32x4 v4 = *reinterpret_cast<const f32x4*>(vals + base);
            rr[ch*4+0] = r4.x; cc[ch*4+0] = c4.x; ff[ch*4+0] = v4.x;
            rr[ch*4+1] = r4.y; cc[ch*4+1] = c4.y; ff[ch*4+1] = v4.y;
            rr[ch*4+2] = r4.z; cc[ch*4+2] = c4.z; ff[ch*4+2] = v4.z;
            rr[ch*4+3] = r4.w; cc[ch*4+3] = c4.w; ff[ch*4+3] = v4.w;
        }
        #pragma unroll
        for (int j = 0; j < 16; ++j) ff[j] *= x[cc[j]];
    } else {
        #pragma unroll
        for (int ch = 0; ch < 4; ++ch) {
            #pragma unroll
            for (int j = 0; j < 4; ++j) {
                int idx = seg + ch * 1024 + t * 4 + j;
                if (idx < nnz) { rr[ch*4+j] = rows[idx]; cc[ch*4+j] = cols[idx]; ff[ch*4+j] = vals[idx]; }
                else           { rr[ch*4+j] = -1; cc[ch*4+j] = 0; ff[ch*4+j] = 0.0f; }
            }
        }
        #pragma unroll
        for (int j = 0; j < 16; ++j) if (rr[j] >= 0) ff[j] *= x[cc[j]];
    }

    // Histogram (no-return LDS atomics).
    #pragma unroll
    for (int j = 0; j < 16; ++j)
        if (rr[j] >= 0) atomicAdd(&cnt[rr[j] >> ROW_SHIFT], 1u);
    __syncthreads();

    // Reserve global space per bin + shfl exclusive scan of local counts (wave 0).
    if (t < BINS) {
        unsigned c = cnt[t];
        unsigned r = atomicAdd(&gcur[t * CUR_STRIDE], c);
        unsigned v = c;
        #pragma unroll
        for (int d = 1; d < BINS; d <<= 1) {
            unsigned o = __shfl_up(v, d, 64);
            if (t >= d) v += o;
        }
        unsigned ls = v - c;
        lstart[t] = ls;
        cur2[t]   = ls;
        resv[t]   = r;
    }
    __syncthreads();

    // Pass B: place entries grouped by bin in LDS (no sbin needed).
    #pragma unroll
    for (int j = 0; j < 16; ++j) {
        if (rr[j] >= 0) {
            int b = rr[j] >> ROW_SHIFT;
            unsigned p = atomicAdd(&cur2[b], 1u);
            skey[p] = (unsigned short)(rr[j] & (ROWS_PER_BIN - 1));
            sval[p] = ff[j];
        }
    }
    __syncthreads();

    // Copy-out per bin: wave w owns bins [8w, 8w+8); contiguous LDS run ->
    // contiguous global run (coalesced both sides).
    const int wave = t >> 6, lane = t & 63;
    #pragma unroll
    for (int k = 0; k < BINS / 4; ++k) {
        int b = wave * (BINS / 4) + k;
        unsigned n  = cnt[b];
        unsigned ls = lstart[b];
        unsigned gb = resv[b];
        const size_t binoff = (size_t)b * cap;
        for (unsigned i = lane; i < n; i += 64) {
            unsigned off = gb + i;
            if (off < cap) {
                okeys[binoff + off]    = skey[ls + i];
                ocontrib[binoff + off] = sval[ls + i];
            }
        }
    }
}

// One block per (bin, slice): accumulate slice entries into LDS acc, dump partials.
// 512 thr x 32KB LDS, grid BINS*SL; SL=32 -> 4 blocks/CU x 8 waves = 100% occupancy.
template <int SL>
__global__ __launch_bounds__(512) void accum2_kernel(
    const unsigned short* __restrict__ okeys, const float* __restrict__ ocontrib,
    const unsigned* __restrict__ gcur, unsigned cap,
    float* __restrict__ partials)
{
    __shared__ float acc[ROWS_PER_BIN];
    const int t   = threadIdx.x;
    const int bin = blockIdx.x / SL;
    const int sl  = blockIdx.x - bin * SL;

    float4 z = make_float4(0.f, 0.f, 0.f, 0.f);
    #pragma unroll
    for (int i = 0; i < ROWS_PER_BIN / (512 * 4); ++i)
        *reinterpret_cast<float4*>(&acc[(i * 512 + t) * 4]) = z;
    __syncthreads();

    unsigned count = gcur[bin * CUR_STRIDE];
    if (count > cap) count = cap;
    unsigned chunk = ((count + (unsigned)SL - 1u) / (unsigned)SL + 3u) & ~3u;
    unsigned lo = (unsigned)sl * chunk;
    unsigned hi = lo + chunk; if (hi > count) hi = count;

    const unsigned short* k = okeys    + (size_t)bin * cap;
    const float*          c = ocontrib + (size_t)bin * cap;

    unsigned i = lo + (unsigned)t * 4u;

    // 4x batch: 8 independent vector loads in flight before any LDS atomic.
    for (; i + 6147u < hi; i += 8192u) {
        ushort4 K[4];
        float4  C[4];
        #pragma unroll
        for (int j = 0; j < 4; ++j) K[j] = *reinterpret_cast<const ushort4*>(k + i + (unsigned)j * 2048u);
        #pragma unroll
        for (int j = 0; j < 4; ++j) C[j] = *reinterpret_cast<const float4*>(c + i + (unsigned)j * 2048u);
        #pragma unroll
        for (int j = 0; j < 4; ++j) {
            atomicAdd(&acc[K[j].x], C[j].x);
            atomicAdd(&acc[K[j].y], C[j].y);
            atomicAdd(&acc[K[j].z], C[j].z);
            atomicAdd(&acc[K[j].w], C[j].w);
        }
    }
    for (; i + 3u < hi; i += 2048u) {
        ushort4 k4 = *reinterpret_cast<const ushort4*>(k + i);
        float4  c4 = *reinterpret_cast<const float4*>(c + i);
        atomicAdd(&acc[k4.x], c4.x);
        atomicAdd(&acc[k4.y], c4.y);
        atomicAdd(&acc[k4.z], c4.z);
        atomicAdd(&acc[k4.w], c4.w);
    }
    for (; i < hi; ++i) atomicAdd(&acc[k[i]], c[i]);
    __syncthreads();

    float* p = partials + (size_t)blockIdx.x * ROWS_PER_BIN;
    #pragma unroll
    for (int i2 = 0; i2 < ROWS_PER_BIN / (512 * 4); ++i2) {
        int l = (i2 * 512 + t) * 4;
        *reinterpret_cast<float4*>(p + l) = *reinterpret_cast<const float4*>(&acc[l]);
    }
}

// Sum the SL partials per row, 4 rows per thread (float4).
template <int SL>
__global__ __launch_bounds__(256) void reduce2_kernel(
    const float* __restrict__ partials, float* __restrict__ y, int out_size)
{
    int r0 = (blockIdx.x * 256 + threadIdx.x) * 4;
    if (r0 >= out_size) return;
    int bin = r0 >> ROW_SHIFT, local = r0 & (ROWS_PER_BIN - 1);
    const float* p = partials + ((size_t)bin * SL) * ROWS_PER_BIN + local;
    float4 s = make_float4(0.f, 0.f, 0.f, 0.f);
    #pragma unroll
    for (int j = 0; j < SL; ++j) {
        float4 v = *reinterpret_cast<const float4*>(p + (size_t)j * ROWS_PER_BIN);
        s.x += v.x; s.y += v.y; s.z += v.z; s.w += v.w;
    }
    *reinterpret_cast<float4*>(y + r0) = s;
}

extern "C" void kernel_launch(void* const* d_in, const int* in_sizes, int n_in,
                              void* d_out, int out_size, void* d_ws, size_t ws_size,
                              hipStream_t stream) {
    const float* x    = (const float*)d_in[0];
    const float* vals = (const float*)d_in[1];
    const int*   rows = (const int*)d_in[2];
    const int*   cols = (const int*)d_in[3];
    float* y = (float*)d_out;

    const int nnz  = in_sizes[1];
    const int bins = (out_size + ROWS_PER_BIN - 1) / ROWS_PER_BIN;

    unsigned cap = (unsigned)(nnz / (bins > 0 ? bins : 1)) + 16384u;   // ~32 sigma slack
    cap = (cap + 3u) & ~3u;

    auto align256 = [](size_t v) { return (v + 255) & ~(size_t)255; };

    int slices = 32;
    size_t off_contrib = 0, off_keys = 0, off_partials = 0, off_gcur = 0, need = 0;
    for (int attempt = 0; attempt < 2; ++attempt) {
        off_contrib  = 0;
        off_keys     = align256(off_contrib + (size_t)BINS * cap * 4);
        off_partials = align256(off_keys + (size_t)BINS * cap * 2);
        off_gcur     = align256(off_partials + (size_t)BINS * slices * ROWS_PER_BIN * 4);
        need         = align256(off_gcur + (size_t)BINS * CUR_STRIDE * 4);
        if (need <= ws_size) break;
        slices = 16;                     // shrink partials if workspace is tight
    }

    const bool ok = (bins == BINS) && (need <= ws_size) && (nnz > 0) &&
                    (out_size == BINS * ROWS_PER_BIN);

    if (!ok) {
        zero_out_kernel<<<(out_size + 255) / 256, 256, 0, stream>>>(y, out_size);
        spmv_coo_scatter<<<(nnz + 1023) / 1024, 256, 0, stream>>>(vals, rows, cols, x, y, nnz);
        return;
    }

    char* w = (char*)d_ws;
    float*          ocontrib = (float*)(w + off_contrib);
    unsigned short* okeys    = (unsigned short*)(w + off_keys);
    float*          partials = (float*)(w + off_partials);
    unsigned*       gcur     = (unsigned*)(w + off_gcur);

    const int ncur = BINS * CUR_STRIDE;
    init_cursors<<<(ncur + 255) / 256, 256, 0, stream>>>(gcur, ncur);
    scatter2_kernel<<<(nnz + ENT - 1) / ENT, 256, 0, stream>>>(
        rows, cols, vals, x, nnz, gcur, cap, okeys, ocontrib);

    if (slices == 32) {
        accum2_kernel<32><<<BINS * 32, 512, 0, stream>>>(okeys, ocontrib, gcur, cap, partials);
        reduce2_kernel<32><<<(out_size / 4 + 255) / 256, 256, 0, stream>>>(partials, y, out_size);
    } else {
        accum2_kernel<16><<<BINS * 16, 512, 0, stream>>>(okeys, ocontrib, gcur, cap, partials);
        reduce2_kernel<16><<<(out_size / 4 + 255) / 256, 256, 0, stream>>>(partials, y, out_size);
    }
}